// Round 4
// baseline (8848.210 us; speedup 1.0000x reference)
//
#include <hip/hip_runtime.h>

#define NN 100000
#define NE 1600000
#define NG 64

typedef __attribute__((ext_vector_type(8))) short bf16x8;
typedef __attribute__((ext_vector_type(4))) float f32x4;

__device__ __forceinline__ unsigned short f2bf(float f) {
  unsigned u = __float_as_uint(f);
  unsigned r = u + 0x7FFFu + ((u >> 16) & 1u);
  return (unsigned short)(r >> 16);
}
__device__ __forceinline__ float bf2f(unsigned u16) {
  return __uint_as_float(u16 << 16);
}

__device__ __forceinline__ float wave_sum(float v) {
#pragma unroll
  for (int off = 32; off; off >>= 1) v += __shfl_down(v, off, 64);
  return v;
}
__device__ __forceinline__ float wave_max(float v) {
#pragma unroll
  for (int off = 32; off; off >>= 1) v = fmaxf(v, __shfl_down(v, off, 64));
  return v;
}

// read one MFMA fragment (16B) from a swizzled [rows][256B] LDS tile image
__device__ __forceinline__ bf16x8 frag_ld(const char* base, int row, int kbyte) {
  return *(const bf16x8*)(base + row * 256 + (kbyte ^ ((row & 7) << 4)));
}

// ---------------- fused message pass v2: edge-parallel LDS scatter + MFMA ----------------
// CSR keyed b = et*NN + dst; payload = src | ((dst&63)<<17)
__global__ void __launch_bounds__(256)
msg_mfma2(const unsigned* __restrict__ hbf32, const int* __restrict__ rowst,
          const int* __restrict__ payload, const unsigned short* __restrict__ Wmsg,
          const float* __restrict__ bmsg, float* __restrict__ af) {
  __shared__ float accf[64 * 132];  // padded rows (132) to avoid bank conflicts
  const int tid = threadIdx.x, lane = tid & 63, wid = tid >> 6;
  const int l15 = lane & 15, lhi = lane >> 4;
  const int bm = blockIdx.x * 64;
  const int wrow0 = (wid >> 1) * 32, wcol0 = (wid & 1) * 64;
  const int nend = min(bm + 64, NN);

  f32x4 acc[8];
#pragma unroll
  for (int f = 0; f < 8; ++f)
#pragma unroll
    for (int r = 0; r < 4; ++r) acc[f][r] = 0.f;

  for (int et = 0; et < 3; ++et) {
    __syncthreads();  // previous MFMA phase done reading accf
    for (int i = tid; i < 64 * 132; i += 256) accf[i] = 0.f;
    __syncthreads();

    const int segs = rowst[et * NN + bm];
    const int sege = rowst[et * NN + nend];
    const int len = sege - segs;
    const int chunk = (len + 3) >> 2;
    const int ws = segs + wid * chunk;
    const int we = min(ws + chunk, sege);
    int i = ws;
    for (; i + 4 <= we; i += 4) {
      int p0 = payload[i], p1 = payload[i + 1], p2 = payload[i + 2], p3 = payload[i + 3];
      unsigned v0 = hbf32[(size_t)(p0 & 0x1FFFF) * 64 + lane];
      unsigned v1 = hbf32[(size_t)(p1 & 0x1FFFF) * 64 + lane];
      unsigned v2 = hbf32[(size_t)(p2 & 0x1FFFF) * 64 + lane];
      unsigned v3 = hbf32[(size_t)(p3 & 0x1FFFF) * 64 + lane];
      atomicAdd(&accf[(p0 >> 17) * 132 + 2 * lane], bf2f(v0 & 0xffffu));
      atomicAdd(&accf[(p0 >> 17) * 132 + 2 * lane + 1], bf2f(v0 >> 16));
      atomicAdd(&accf[(p1 >> 17) * 132 + 2 * lane], bf2f(v1 & 0xffffu));
      atomicAdd(&accf[(p1 >> 17) * 132 + 2 * lane + 1], bf2f(v1 >> 16));
      atomicAdd(&accf[(p2 >> 17) * 132 + 2 * lane], bf2f(v2 & 0xffffu));
      atomicAdd(&accf[(p2 >> 17) * 132 + 2 * lane + 1], bf2f(v2 >> 16));
      atomicAdd(&accf[(p3 >> 17) * 132 + 2 * lane], bf2f(v3 & 0xffffu));
      atomicAdd(&accf[(p3 >> 17) * 132 + 2 * lane + 1], bf2f(v3 >> 16));
    }
    for (; i < we; ++i) {
      int p0 = payload[i];
      unsigned v0 = hbf32[(size_t)(p0 & 0x1FFFF) * 64 + lane];
      atomicAdd(&accf[(p0 >> 17) * 132 + 2 * lane], bf2f(v0 & 0xffffu));
      atomicAdd(&accf[(p0 >> 17) * 132 + 2 * lane + 1], bf2f(v0 >> 16));
    }
    __syncthreads();

    // MFMA: A = hi/lo split of fp32 accumulators, B streamed from global (L2-hot)
#pragma unroll
    for (int ks = 0; ks < 4; ++ks) {
      bf16x8 ahi[2], alo[2];
#pragma unroll
      for (int mf = 0; mf < 2; ++mf) {
        int row = wrow0 + mf * 16 + l15;
        const float* pr = accf + row * 132 + ks * 32 + lhi * 8;
        f32x4 x0 = *(const f32x4*)pr;
        f32x4 x1 = *(const f32x4*)(pr + 4);
#pragma unroll
        for (int j = 0; j < 4; ++j) {
          unsigned short h0 = f2bf(x0[j]);
          ahi[mf][j] = (short)h0;
          alo[mf][j] = (short)f2bf(x0[j] - bf2f(h0));
          unsigned short h1 = f2bf(x1[j]);
          ahi[mf][4 + j] = (short)h1;
          alo[mf][4 + j] = (short)f2bf(x1[j] - bf2f(h1));
        }
      }
#pragma unroll
      for (int nf = 0; nf < 4; ++nf) {
        int col = wcol0 + nf * 16 + l15;
        bf16x8 bfr = *(const bf16x8*)((const char*)Wmsg +
                       ((size_t)et * 128 + col) * 256 + ks * 64 + lhi * 16);
#pragma unroll
        for (int mf = 0; mf < 2; ++mf) {
          acc[mf * 4 + nf] = __builtin_amdgcn_mfma_f32_16x16x32_bf16(
              ahi[mf], bfr, acc[mf * 4 + nf], 0, 0, 0);
          acc[mf * 4 + nf] = __builtin_amdgcn_mfma_f32_16x16x32_bf16(
              alo[mf], bfr, acc[mf * 4 + nf], 0, 0, 0);
        }
      }
    }
  }

  // epilogue: deg-weighted bias (degs from rowst diffs), store fp32 a
#pragma unroll
  for (int mf = 0; mf < 2; ++mf)
#pragma unroll
    for (int r = 0; r < 4; ++r) {
      int grow = bm + wrow0 + mf * 16 + lhi * 4 + r;
      if (grow >= NN) continue;
      float d0 = (float)(rowst[grow + 1] - rowst[grow]);
      float d1 = (float)(rowst[NN + grow + 1] - rowst[NN + grow]);
      float d2 = (float)(rowst[2 * NN + grow + 1] - rowst[2 * NN + grow]);
#pragma unroll
      for (int nf = 0; nf < 4; ++nf) {
        int col = wcol0 + nf * 16 + l15;
        af[(size_t)grow * 128 + col] = acc[mf * 4 + nf][r] + d0 * bmsg[col] +
                                       d1 * bmsg[128 + col] + d2 * bmsg[256 + col];
      }
    }
}

// ---------------- fused GRU v2: hi/lo A-tiles, B from global, 1 barrier ----------------
__global__ void __launch_bounds__(256)
gru_mfma2(float* __restrict__ hf, unsigned short* __restrict__ hbf,
          const float* __restrict__ af, const unsigned short* __restrict__ Wih,
          const unsigned short* __restrict__ Whh, const float* __restrict__ bih,
          const float* __restrict__ bhh) {
  __shared__ char Aah[16384];  // a hi
  __shared__ char Aal[16384];  // a lo
  __shared__ char Ahh[16384];  // h hi
  __shared__ char Ahl[16384];  // h lo
  const int tid = threadIdx.x, lane = tid & 63, wid = tid >> 6;
  const int l15 = lane & 15, lhi = lane >> 4;
  const int bm = blockIdx.x * 64;
  const int wrow0 = (wid >> 1) * 32, wcol0 = (wid & 1) * 64;

  for (int idx = tid; idx < 2048; idx += 256) {
    int row = idx >> 5, seg = idx & 31;
    int gr = bm + row;
    float4 va = make_float4(0.f, 0.f, 0.f, 0.f);
    float4 vh = make_float4(0.f, 0.f, 0.f, 0.f);
    if (gr < NN) {
      va = *(const float4*)(af + (size_t)gr * 128 + seg * 4);
      vh = *(const float4*)(hf + (size_t)gr * 128 + seg * 4);
    }
    int so = row * 256 + ((seg * 8) ^ ((row & 7) << 4));
    {
      unsigned short h0 = f2bf(va.x), h1 = f2bf(va.y), h2 = f2bf(va.z), h3 = f2bf(va.w);
      uint2 hp, lp;
      hp.x = (unsigned)h0 | ((unsigned)h1 << 16);
      hp.y = (unsigned)h2 | ((unsigned)h3 << 16);
      lp.x = (unsigned)f2bf(va.x - bf2f(h0)) | ((unsigned)f2bf(va.y - bf2f(h1)) << 16);
      lp.y = (unsigned)f2bf(va.z - bf2f(h2)) | ((unsigned)f2bf(va.w - bf2f(h3)) << 16);
      *(uint2*)(Aah + so) = hp;
      *(uint2*)(Aal + so) = lp;
    }
    {
      unsigned short h0 = f2bf(vh.x), h1 = f2bf(vh.y), h2 = f2bf(vh.z), h3 = f2bf(vh.w);
      uint2 hp, lp;
      hp.x = (unsigned)h0 | ((unsigned)h1 << 16);
      hp.y = (unsigned)h2 | ((unsigned)h3 << 16);
      lp.x = (unsigned)f2bf(vh.x - bf2f(h0)) | ((unsigned)f2bf(vh.y - bf2f(h1)) << 16);
      lp.y = (unsigned)f2bf(vh.z - bf2f(h2)) | ((unsigned)f2bf(vh.w - bf2f(h3)) << 16);
      *(uint2*)(Ahh + so) = hp;
      *(uint2*)(Ahl + so) = lp;
    }
  }
  __syncthreads();

  f32x4 rr[8], zz[8];
  for (int gate = 0; gate < 3; ++gate) {
    f32x4 acc_i[8], acc_h[8];
#pragma unroll
    for (int f = 0; f < 8; ++f)
#pragma unroll
      for (int r = 0; r < 4; ++r) { acc_i[f][r] = 0.f; acc_h[f][r] = 0.f; }

#pragma unroll
    for (int ks = 0; ks < 4; ++ks) {
      int kb = ks * 64 + lhi * 16;
      bf16x8 fah[2], fal[2], fhh[2], fhl[2];
#pragma unroll
      for (int mf = 0; mf < 2; ++mf) {
        int row = wrow0 + mf * 16 + l15;
        fah[mf] = frag_ld(Aah, row, kb);
        fal[mf] = frag_ld(Aal, row, kb);
        fhh[mf] = frag_ld(Ahh, row, kb);
        fhl[mf] = frag_ld(Ahl, row, kb);
      }
#pragma unroll
      for (int nf = 0; nf < 4; ++nf) {
        size_t wo = ((size_t)(gate * 128 + wcol0 + nf * 16 + l15)) * 256 + kb;
        bf16x8 bi = *(const bf16x8*)((const char*)Wih + wo);
        bf16x8 bh = *(const bf16x8*)((const char*)Whh + wo);
#pragma unroll
        for (int mf = 0; mf < 2; ++mf) {
          int f = mf * 4 + nf;
          acc_i[f] = __builtin_amdgcn_mfma_f32_16x16x32_bf16(fah[mf], bi, acc_i[f], 0, 0, 0);
          acc_i[f] = __builtin_amdgcn_mfma_f32_16x16x32_bf16(fal[mf], bi, acc_i[f], 0, 0, 0);
          acc_h[f] = __builtin_amdgcn_mfma_f32_16x16x32_bf16(fhh[mf], bh, acc_h[f], 0, 0, 0);
          acc_h[f] = __builtin_amdgcn_mfma_f32_16x16x32_bf16(fhl[mf], bh, acc_h[f], 0, 0, 0);
        }
      }
    }

    if (gate < 2) {
#pragma unroll
      for (int mf = 0; mf < 2; ++mf)
#pragma unroll
        for (int nf = 0; nf < 4; ++nf) {
          int f = mf * 4 + nf;
          int col = wcol0 + nf * 16 + l15;
          float bi = bih[gate * 128 + col], bh = bhh[gate * 128 + col];
#pragma unroll
          for (int r = 0; r < 4; ++r) {
            float v = acc_i[f][r] + acc_h[f][r] + bi + bh;
            float sg = 1.f / (1.f + __expf(-v));
            if (gate == 0) rr[f][r] = sg;
            else zz[f][r] = sg;
          }
        }
    } else {
#pragma unroll
      for (int mf = 0; mf < 2; ++mf)
#pragma unroll
        for (int r = 0; r < 4; ++r) {
          int lrow = wrow0 + mf * 16 + lhi * 4 + r;
          int grow = bm + lrow;
          if (grow >= NN) continue;
#pragma unroll
          for (int nf = 0; nf < 4; ++nf) {
            int f = mf * 4 + nf;
            int col = wcol0 + nf * 16 + l15;
            float in_ = acc_i[f][r] + bih[256 + col];
            float hn = acc_h[f][r] + bhh[256 + col];
            float x = in_ + rr[f][r] * hn;
            float e = __expf(-2.f * x);
            float n = (1.f - e) / (1.f + e);
            float z = zz[f][r];
            int off = lrow * 256 + ((col * 2) ^ ((lrow & 7) << 4));
            float ho = bf2f(*(const unsigned short*)(Ahh + off)) +
                       bf2f(*(const unsigned short*)(Ahl + off));
            float hv = (1.f - z) * n + z * ho;
            hf[(size_t)grow * 128 + col] = hv;
            hbf[(size_t)grow * 128 + col] = f2bf(hv);
          }
        }
    }
  }
}

// ---------- fp32 GEMM for h0 (B streamed from cache) ----------
template <int KD>
__global__ void __launch_bounds__(256)
gemm_cacheB(const float* __restrict__ X, const int* __restrict__ rowidx,
            const float* __restrict__ B, int ldb, const float* __restrict__ bias,
            float* __restrict__ C, float* __restrict__ C2, int M) {
  __shared__ float xs[KD * 64];
  constexpr int KC = KD / 4;
  const int tid = threadIdx.x;
  const int bm = blockIdx.x * 64;

  for (int idx = tid; idx < 64 * KC; idx += 256) {
    int m = idx / KC, c = idx - m * KC;
    int gm = bm + m;
    float4 v = make_float4(0.f, 0.f, 0.f, 0.f);
    if (gm < M) {
      int r = rowidx ? rowidx[gm] : gm;
      v = *(const float4*)(X + (size_t)r * KD + 4 * c);
    }
    int k0 = 4 * c;
    xs[(k0 + 0) * 64 + ((((m >> 2) ^ ((k0 + 0) & 15)) << 2) | (m & 3))] = v.x;
    xs[(k0 + 1) * 64 + ((((m >> 2) ^ ((k0 + 1) & 15)) << 2) | (m & 3))] = v.y;
    xs[(k0 + 2) * 64 + ((((m >> 2) ^ ((k0 + 2) & 15)) << 2) | (m & 3))] = v.z;
    xs[(k0 + 3) * 64 + ((((m >> 2) ^ ((k0 + 3) & 15)) << 2) | (m & 3))] = v.w;
  }
  __syncthreads();

  const int tx = tid & 15, ty = tid >> 4;
  float acc[4][8] = {};
#pragma unroll 4
  for (int k = 0; k < KD; ++k) {
    float4 a = *(float4*)(xs + k * 64 + ((ty ^ (k & 15)) << 2));
    float4 b0 = *(const float4*)(B + (size_t)k * ldb + 4 * tx);
    float4 b1 = *(const float4*)(B + (size_t)k * ldb + 64 + 4 * tx);
    float av[4] = {a.x, a.y, a.z, a.w};
    float bv[8] = {b0.x, b0.y, b0.z, b0.w, b1.x, b1.y, b1.z, b1.w};
#pragma unroll
    for (int i = 0; i < 4; ++i)
#pragma unroll
      for (int j = 0; j < 8; ++j) acc[i][j] += av[i] * bv[j];
  }

#pragma unroll
  for (int i = 0; i < 4; ++i) {
    int gm = bm + 4 * ty + i;
    if (gm >= M) continue;
    float4 o0, o1;
    o0.x = acc[i][0] + bias[4 * tx + 0];
    o0.y = acc[i][1] + bias[4 * tx + 1];
    o0.z = acc[i][2] + bias[4 * tx + 2];
    o0.w = acc[i][3] + bias[4 * tx + 3];
    o1.x = acc[i][4] + bias[64 + 4 * tx + 0];
    o1.y = acc[i][5] + bias[64 + 4 * tx + 1];
    o1.z = acc[i][6] + bias[64 + 4 * tx + 2];
    o1.w = acc[i][7] + bias[64 + 4 * tx + 3];
    *(float4*)(C + (size_t)gm * 128 + 4 * tx) = o0;
    *(float4*)(C + (size_t)gm * 128 + 64 + 4 * tx) = o1;
    if (C2) {
      *(float4*)(C2 + (size_t)gm * 128 + 4 * tx) = o0;
      *(float4*)(C2 + (size_t)gm * 128 + 64 + 4 * tx) = o1;
    }
  }
}

// ---------- CSR build keyed by b = et*NN + dst ----------
__global__ void count3_k(const int* __restrict__ dst, const int* __restrict__ et,
                         int* __restrict__ deg3) {
  int e = blockIdx.x * 256 + threadIdx.x;
  if (e < NE) atomicAdd(&deg3[et[e] * NN + dst[e]], 1);
}
__global__ void scan1(const int* __restrict__ deg, int* __restrict__ rowst,
                      int* __restrict__ csum, int L) {
  __shared__ int s[256];
  int base = blockIdx.x * 1024;
  int tid = threadIdx.x;
  int v[4], pre[4];
  int run = 0;
#pragma unroll
  for (int j = 0; j < 4; ++j) {
    int idx = base + tid * 4 + j;
    v[j] = (idx < L) ? deg[idx] : 0;
    pre[j] = run;
    run += v[j];
  }
  s[tid] = run;
  __syncthreads();
  for (int off = 1; off < 256; off <<= 1) {
    int t = (tid >= off) ? s[tid - off] : 0;
    __syncthreads();
    s[tid] += t;
    __syncthreads();
  }
  int excl = (tid == 0) ? 0 : s[tid - 1];
#pragma unroll
  for (int j = 0; j < 4; ++j) {
    int idx = base + tid * 4 + j;
    if (idx < L) rowst[idx] = excl + pre[j];
  }
  if (tid == 255) csum[blockIdx.x] = s[255];
}
__global__ void scan2(int* csum, int nch) {
  if (threadIdx.x == 0 && blockIdx.x == 0) {
    int run = 0;
    for (int i = 0; i < nch; ++i) { int t = csum[i]; csum[i] = run; run += t; }
  }
}
__global__ void scan3(int* rowst, const int* __restrict__ csum, int L) {
  int idx = blockIdx.x * 256 + threadIdx.x;
  if (idx < L) rowst[idx] += csum[idx >> 10];
}
__global__ void set_last(int* rowst) { rowst[3 * NN] = NE; }
__global__ void fill3_k(const int* __restrict__ src, const int* __restrict__ dst,
                        const int* __restrict__ et, const int* __restrict__ rowst3,
                        int* __restrict__ cursor3, int* __restrict__ payload) {
  int e = blockIdx.x * 256 + threadIdx.x;
  if (e >= NE) return;
  int b3 = et[e] * NN + dst[e];
  int pos = rowst3[b3] + atomicAdd(&cursor3[b3], 1);
  payload[pos] = src[e] | ((dst[e] & 63) << 17);
}

// ---------- misc ----------
__global__ void transpose_w(const float* __restrict__ W, float* __restrict__ WT,
                            int J, int Kd) {
  int idx = blockIdx.x * 256 + threadIdx.x;
  if (idx >= J * Kd) return;
  int j = idx / Kd, k = idx - j * Kd;
  WT[(size_t)k * J + j] = W[idx];
}

__global__ void conv_bf16v(const float* __restrict__ s, unsigned short* __restrict__ d,
                           int n4) {
  int i = blockIdx.x * 256 + threadIdx.x;
  if (i >= n4) return;
  float4 v = *(const float4*)(s + 4 * (size_t)i);
  unsigned lo = (unsigned)f2bf(v.x) | ((unsigned)f2bf(v.y) << 16);
  unsigned hi = (unsigned)f2bf(v.z) | ((unsigned)f2bf(v.w) << 16);
  *(unsigned*)(d + 4 * (size_t)i) = lo;
  *(unsigned*)(d + 4 * (size_t)i + 2) = hi;
}

__global__ void __launch_bounds__(256)
gate_k(const float* __restrict__ h, const float* __restrict__ h0,
       const float* __restrict__ Wg, const float* __restrict__ bg,
       float* __restrict__ gate) {
  int wid = threadIdx.x >> 6, lane = threadIdx.x & 63;
  int n = blockIdx.x * 4 + wid;
  if (n >= NN) return;
  float2 hv = *(const float2*)(h + (size_t)n * 128 + 2 * lane);
  float2 h0v = *(const float2*)(h0 + (size_t)n * 128 + 2 * lane);
  float p = hv.x * Wg[2 * lane] + hv.y * Wg[2 * lane + 1] +
            h0v.x * Wg[128 + 2 * lane] + h0v.y * Wg[128 + 2 * lane + 1];
  p = wave_sum(p);
  if (lane == 0) gate[n] = p + bg[0];
}

__global__ void bounds_k(const int* __restrict__ gid, int* __restrict__ bound) {
  int g = threadIdx.x;
  if (g > NG) return;
  int lo = 0, hi = NN;
  while (lo < hi) {
    int mid = (lo + hi) >> 1;
    if (gid[mid] < g) lo = mid + 1; else hi = mid;
  }
  bound[g] = lo;
}

__global__ void __launch_bounds__(256)
pool_k(const float* __restrict__ h, const float* __restrict__ h0,
       const float* __restrict__ gate, const int* __restrict__ bound,
       const float* __restrict__ Wout, const float* __restrict__ bout,
       float* __restrict__ out) {
  int g = blockIdx.x;
  int s = bound[g], e = bound[g + 1];
  __shared__ float sred[4];
  __shared__ float sbc[2];
  __shared__ float facc[1024];
  int tid = threadIdx.x, wid = tid >> 6, lane = tid & 63;
  if (s >= e) { if (tid == 0) out[g] = bout[0]; return; }

  float mx = -3.4e38f;
  for (int i = s + tid; i < e; i += 256) mx = fmaxf(mx, gate[i]);
  mx = wave_max(mx);
  if (lane == 0) sred[wid] = mx;
  __syncthreads();
  if (tid == 0) sbc[0] = fmaxf(fmaxf(sred[0], sred[1]), fmaxf(sred[2], sred[3]));
  __syncthreads();
  float mglob = sbc[0];

  float ss = 0.f;
  for (int i = s + tid; i < e; i += 256) ss += expf(gate[i] - mglob);
  ss = wave_sum(ss);
  if (lane == 0) sred[wid] = ss;
  __syncthreads();
  if (tid == 0) sbc[1] = sred[0] + sred[1] + sred[2] + sred[3];
  __syncthreads();
  float S = sbc[1];

  float a0 = 0.f, a1 = 0.f, a2 = 0.f, a3 = 0.f;
  for (int n = s + wid; n < e; n += 4) {
    float alpha = expf(gate[n] - mglob) / S;
    const float* p = (lane < 32) ? (h + (size_t)n * 128 + 4 * lane)
                                 : (h0 + (size_t)n * 128 + 4 * (lane - 32));
    float4 v = *(const float4*)p;
    a0 += alpha * v.x; a1 += alpha * v.y; a2 += alpha * v.z; a3 += alpha * v.w;
  }
  facc[wid * 256 + 4 * lane + 0] = a0;
  facc[wid * 256 + 4 * lane + 1] = a1;
  facc[wid * 256 + 4 * lane + 2] = a2;
  facc[wid * 256 + 4 * lane + 3] = a3;
  __syncthreads();
  float rsum = facc[tid] + facc[256 + tid] + facc[512 + tid] + facc[768 + tid];
  float val = rsum * Wout[tid];
  val = wave_sum(val);
  if (lane == 0) sred[wid] = val;
  __syncthreads();
  if (tid == 0) out[g] = sred[0] + sred[1] + sred[2] + sred[3] + bout[0];
}

// ---------- host ----------
extern "C" void kernel_launch(void* const* d_in, const int* in_sizes, int n_in,
                              void* d_out, int out_size, void* d_ws, size_t ws_size,
                              hipStream_t stream) {
  (void)in_sizes; (void)n_in; (void)out_size; (void)ws_size;
  const int* type_ids = (const int*)d_in[0];
  const int* src      = (const int*)d_in[1];
  const int* dst      = (const int*)d_in[2];
  const int* etypes   = (const int*)d_in[3];
  const int* gid      = (const int*)d_in[4];
  const float* embed  = (const float*)d_in[5];
  const float* W_red  = (const float*)d_in[6];
  const float* b_red  = (const float*)d_in[7];
  const float* W_msg  = (const float*)d_in[8];
  const float* b_msg  = (const float*)d_in[9];
  const float* W_ih   = (const float*)d_in[10];
  const float* b_ih   = (const float*)d_in[11];
  const float* W_hh   = (const float*)d_in[12];
  const float* b_hh   = (const float*)d_in[13];
  const float* W_gate = (const float*)d_in[14];
  const float* b_gate = (const float*)d_in[15];
  const float* W_out  = (const float*)d_in[16];
  const float* b_out  = (const float*)d_in[17];

  char* p = (char*)d_ws;
  auto take = [&](size_t nb) { char* r = p; p += (nb + 255) & ~(size_t)255; return r; };
  float* hf            = (float*)take((size_t)NN * 128 * sizeof(float));
  float* h0b           = (float*)take((size_t)NN * 128 * sizeof(float));
  float* af            = (float*)take((size_t)NN * 128 * sizeof(float));
  unsigned short* hbf  = (unsigned short*)take((size_t)NN * 128 * 2);
  unsigned short* WmsgB = (unsigned short*)take(49152 * 2);
  unsigned short* WihB  = (unsigned short*)take(49152 * 2);
  unsigned short* WhhB  = (unsigned short*)take(49152 * 2);
  float* WredT = (float*)take(64 * 128 * sizeof(float));
  float* gateb = (float*)take((size_t)NN * sizeof(float));
  int* deg3    = (int*)take((size_t)2 * 3 * NN * sizeof(int));
  int* cursor3 = deg3 + 3 * NN;
  int* rowst3x = (int*)take(((size_t)3 * NN + 1) * sizeof(int));
  int* payload = (int*)take((size_t)NE * sizeof(int));
  int* csum    = (int*)take(2048);
  int* bound   = (int*)take(512);

  // weight prep
  transpose_w<<<(128 * 64 + 255) / 256, 256, 0, stream>>>(W_red, WredT, 128, 64);
  conv_bf16v<<<(49152 / 4 + 255) / 256, 256, 0, stream>>>(W_msg, WmsgB, 49152 / 4);
  conv_bf16v<<<(49152 / 4 + 255) / 256, 256, 0, stream>>>(W_ih, WihB, 49152 / 4);
  conv_bf16v<<<(49152 / 4 + 255) / 256, 256, 0, stream>>>(W_hh, WhhB, 49152 / 4);

  // CSR keyed by (etype, dst)
  const int L3 = 3 * NN;
  hipMemsetAsync(deg3, 0, (size_t)2 * L3 * sizeof(int), stream);
  count3_k<<<(NE + 255) / 256, 256, 0, stream>>>(dst, etypes, deg3);
  int nch = (L3 + 1023) / 1024;
  scan1<<<nch, 256, 0, stream>>>(deg3, rowst3x, csum, L3);
  scan2<<<1, 64, 0, stream>>>(csum, nch);
  scan3<<<(L3 + 255) / 256, 256, 0, stream>>>(rowst3x, csum, L3);
  set_last<<<1, 1, 0, stream>>>(rowst3x);
  fill3_k<<<(NE + 255) / 256, 256, 0, stream>>>(src, dst, etypes, rowst3x, cursor3, payload);

  // h0 = embed[type_ids] @ W_red^T + b_red ; hf = h0 ; hbf shadow
  gemm_cacheB<64><<<(NN + 63) / 64, 256, 0, stream>>>(
      embed, type_ids, WredT, 128, b_red, h0b, hf, NN);
  conv_bf16v<<<((NN * 128 / 4) + 255) / 256, 256, 0, stream>>>(hf, hbf, NN * 128 / 4);

  const int nblk = (NN + 63) / 64;
  for (int s6 = 0; s6 < 6; ++s6) {
    msg_mfma2<<<nblk, 256, 0, stream>>>((const unsigned*)hbf, rowst3x, payload,
                                        WmsgB, b_msg, af);
    gru_mfma2<<<nblk, 256, 0, stream>>>(hf, hbf, af, WihB, WhhB, b_ih, b_hh);
  }

  gate_k<<<(NN + 3) / 4, 256, 0, stream>>>(hf, h0b, W_gate, b_gate, gateb);
  bounds_k<<<1, 128, 0, stream>>>(gid, bound);
  pool_k<<<NG, 256, 0, stream>>>(hf, h0b, gateb, bound, W_out, b_out, (float*)d_out);
}

// Round 5
// 3547.406 us; speedup vs baseline: 2.4943x; 2.4943x over previous
//
#include <hip/hip_runtime.h>

#define NN 100000
#define NE 1600000
#define NG 64

typedef __attribute__((ext_vector_type(8))) short bf16x8;
typedef __attribute__((ext_vector_type(4))) float f32x4;

__device__ __forceinline__ unsigned short f2bf(float f) {
  unsigned u = __float_as_uint(f);
  unsigned r = u + 0x7FFFu + ((u >> 16) & 1u);
  return (unsigned short)(r >> 16);
}
__device__ __forceinline__ float bf2f(unsigned u16) {
  return __uint_as_float(u16 << 16);
}

__device__ __forceinline__ float wave_sum(float v) {
#pragma unroll
  for (int off = 32; off; off >>= 1) v += __shfl_down(v, off, 64);
  return v;
}
__device__ __forceinline__ float wave_max(float v) {
#pragma unroll
  for (int off = 32; off; off >>= 1) v = fmaxf(v, __shfl_down(v, off, 64));
  return v;
}

// read one MFMA fragment (16B) from a swizzled [rows][256B] LDS tile image
__device__ __forceinline__ bf16x8 frag_ld(const char* base, int row, int kbyte) {
  return *(const bf16x8*)(base + row * 256 + (kbyte ^ ((row & 7) << 4)));
}

// async global->LDS: 4 bytes per lane, wave-uniform LDS base + lane*4
__device__ __forceinline__ void gload_lds4(const unsigned* g, unsigned* l) {
  __builtin_amdgcn_global_load_lds(
      (const __attribute__((address_space(1))) unsigned*)g,
      (__attribute__((address_space(3))) unsigned*)l, 4, 0, 0);
}

// ---------------- fragment-major weight repack ----------------
// WF chunk idx = ((g*4+ks)*8 + c)*64 + lane ; chunk = W[g*128 + c*16+(lane&15)][ks*32+(lane>>4)*8 .. +8]
__global__ void pack_fragB(const float* __restrict__ W, unsigned short* __restrict__ WF) {
  int idx = blockIdx.x * 256 + threadIdx.x;
  if (idx >= 3 * 4 * 8 * 64) return;
  int lane = idx & 63;
  int c = (idx >> 6) & 7;
  int ks = (idx >> 9) & 3;
  int g = idx >> 11;
  int col = c * 16 + (lane & 15);
  int k0 = ks * 32 + (lane >> 4) * 8;
  const float* src = W + ((size_t)g * 128 + col) * 128 + k0;
  bf16x8 o;
#pragma unroll
  for (int j = 0; j < 8; ++j) o[j] = (short)f2bf(src[j]);
  *(bf16x8*)(WF + (size_t)idx * 8) = o;
}

// ---------------- fused message pass v3: wave-owned nodes, DMA-staged gather ----------------
// CSR keyed b = et*NN + dst; payload = src | ((dst&63)<<17)
__global__ void __launch_bounds__(256)
msg_mfma3(const unsigned* __restrict__ hbf32, const int* __restrict__ rowst,
          const int* __restrict__ payload, const unsigned short* __restrict__ WmsgF,
          const float* __restrict__ bmsg, float* __restrict__ af) {
  __shared__ float accf[64 * 132];       // padded fp32 accumulator tile
  __shared__ unsigned strip[4 * 16 * 64];  // 4 waves x 16 slots x 256B
  const int tid = threadIdx.x, lane = tid & 63, wid = tid >> 6;
  const int l15 = lane & 15, lhi = lane >> 4;
  const int bm = blockIdx.x * 64;
  const int wrow0 = (wid >> 1) * 32, wcol0 = (wid & 1) * 64;
  const int nend = min(bm + 64, NN);
  unsigned* mystrip = strip + wid * 1024;

  f32x4 acc[8];
#pragma unroll
  for (int f = 0; f < 8; ++f)
#pragma unroll
    for (int r = 0; r < 4; ++r) acc[f][r] = 0.f;

  for (int et = 0; et < 3; ++et) {
    __syncthreads();  // prior MFMA phase done reading accf
    for (int i = tid; i < 64 * 132; i += 256) accf[i] = 0.f;
    __syncthreads();

    int n0 = bm + wid * 16;
    int n1 = min(n0 + 16, nend);
    if (n0 < nend) {
      const int ws = rowst[et * NN + n0];
      const int we = rowst[et * NN + n1];
      float sx = 0.f, sy = 0.f;
      int cur = -1;
      for (int base = ws; base < we; base += 16) {
        int cnt = min(16, we - base);
        int prow[16];
#pragma unroll
        for (int j = 0; j < 16; ++j) {
          if (j < cnt) {
            int p = payload[base + j];
            prow[j] = p >> 17;
            gload_lds4(hbf32 + (size_t)(p & 0x1FFFF) * 64 + lane, mystrip + j * 64);
          }
        }
        asm volatile("s_waitcnt vmcnt(0)" ::: "memory");
        __builtin_amdgcn_sched_barrier(0);
#pragma unroll
        for (int j = 0; j < 16; ++j) {
          if (j < cnt) {
            unsigned v = mystrip[j * 64 + lane];
            int row = prow[j];
            if (row != cur) {
              if (cur >= 0) {
                accf[cur * 132 + 2 * lane] = sx;
                accf[cur * 132 + 2 * lane + 1] = sy;
              }
              cur = row;
              sx = 0.f;
              sy = 0.f;
            }
            sx += bf2f(v & 0xffffu);
            sy += bf2f(v >> 16);
          }
        }
        asm volatile("s_waitcnt lgkmcnt(0)" ::: "memory");
        __builtin_amdgcn_sched_barrier(0);
      }
      if (cur >= 0) {
        accf[cur * 132 + 2 * lane] = sx;
        accf[cur * 132 + 2 * lane + 1] = sy;
      }
    }
    __syncthreads();

    // MFMA accumulate for this etype; B fragments coalesced (fragment-major)
#pragma unroll
    for (int ks = 0; ks < 4; ++ks) {
      bf16x8 afr[2];
#pragma unroll
      for (int mf = 0; mf < 2; ++mf) {
        int row = wrow0 + mf * 16 + l15;
        const float* pr = accf + row * 132 + ks * 32 + lhi * 8;
        f32x4 x0 = *(const f32x4*)pr;
        f32x4 x1 = *(const f32x4*)(pr + 4);
#pragma unroll
        for (int j = 0; j < 4; ++j) {
          afr[mf][j] = (short)f2bf(x0[j]);
          afr[mf][4 + j] = (short)f2bf(x1[j]);
        }
      }
#pragma unroll
      for (int nf = 0; nf < 4; ++nf) {
        bf16x8 bfr = *(const bf16x8*)(WmsgF +
            (((size_t)(et * 4 + ks) * 8 + (wcol0 >> 4) + nf) * 64 + lane) * 8);
#pragma unroll
        for (int mf = 0; mf < 2; ++mf)
          acc[mf * 4 + nf] = __builtin_amdgcn_mfma_f32_16x16x32_bf16(
              afr[mf], bfr, acc[mf * 4 + nf], 0, 0, 0);
      }
    }
  }

  // epilogue: deg-weighted bias (degs from rowst diffs), store fp32 a
#pragma unroll
  for (int mf = 0; mf < 2; ++mf)
#pragma unroll
    for (int r = 0; r < 4; ++r) {
      int grow = bm + wrow0 + mf * 16 + lhi * 4 + r;
      if (grow >= NN) continue;
      float d0 = (float)(rowst[grow + 1] - rowst[grow]);
      float d1 = (float)(rowst[NN + grow + 1] - rowst[NN + grow]);
      float d2 = (float)(rowst[2 * NN + grow + 1] - rowst[2 * NN + grow]);
#pragma unroll
      for (int nf = 0; nf < 4; ++nf) {
        int col = wcol0 + nf * 16 + l15;
        af[(size_t)grow * 128 + col] = acc[mf * 4 + nf][r] + d0 * bmsg[col] +
                                       d1 * bmsg[128 + col] + d2 * bmsg[256 + col];
      }
    }
}

// ---------------- fused GRU v3: bf16 A-tiles in LDS, fragment-major B from global ----------------
__global__ void __launch_bounds__(256)
gru_mfma3(float* __restrict__ hf, unsigned short* __restrict__ hbf,
          const float* __restrict__ af, const unsigned short* __restrict__ WihF,
          const unsigned short* __restrict__ WhhF, const float* __restrict__ bih,
          const float* __restrict__ bhh) {
  __shared__ char Aa[16384];
  __shared__ char Ah[16384];
  const int tid = threadIdx.x, lane = tid & 63, wid = tid >> 6;
  const int l15 = lane & 15, lhi = lane >> 4;
  const int bm = blockIdx.x * 64;
  const int wrow0 = (wid >> 1) * 32, wcol0 = (wid & 1) * 64;

  for (int idx = tid; idx < 2048; idx += 256) {
    int row = idx >> 5, seg = idx & 31;
    int gr = bm + row;
    float4 va = make_float4(0.f, 0.f, 0.f, 0.f);
    float4 vh = make_float4(0.f, 0.f, 0.f, 0.f);
    if (gr < NN) {
      va = *(const float4*)(af + (size_t)gr * 128 + seg * 4);
      vh = *(const float4*)(hf + (size_t)gr * 128 + seg * 4);
    }
    int so = row * 256 + ((seg * 8) ^ ((row & 7) << 4));
    uint2 pa, ph;
    pa.x = (unsigned)f2bf(va.x) | ((unsigned)f2bf(va.y) << 16);
    pa.y = (unsigned)f2bf(va.z) | ((unsigned)f2bf(va.w) << 16);
    ph.x = (unsigned)f2bf(vh.x) | ((unsigned)f2bf(vh.y) << 16);
    ph.y = (unsigned)f2bf(vh.z) | ((unsigned)f2bf(vh.w) << 16);
    *(uint2*)(Aa + so) = pa;
    *(uint2*)(Ah + so) = ph;
  }
  __syncthreads();

  f32x4 rr[8], zz[8];
  for (int gate = 0; gate < 3; ++gate) {
    f32x4 acc_i[8], acc_h[8];
#pragma unroll
    for (int f = 0; f < 8; ++f)
#pragma unroll
      for (int r = 0; r < 4; ++r) { acc_i[f][r] = 0.f; acc_h[f][r] = 0.f; }

#pragma unroll
    for (int ks = 0; ks < 4; ++ks) {
      int kb = ks * 64 + lhi * 16;
      bf16x8 fa[2], fh[2];
#pragma unroll
      for (int mf = 0; mf < 2; ++mf) {
        int row = wrow0 + mf * 16 + l15;
        fa[mf] = frag_ld(Aa, row, kb);
        fh[mf] = frag_ld(Ah, row, kb);
      }
#pragma unroll
      for (int nf = 0; nf < 4; ++nf) {
        size_t fidx = (((size_t)(gate * 4 + ks) * 8 + (wcol0 >> 4) + nf) * 64 + lane) * 8;
        bf16x8 bi = *(const bf16x8*)(WihF + fidx);
        bf16x8 bh = *(const bf16x8*)(WhhF + fidx);
#pragma unroll
        for (int mf = 0; mf < 2; ++mf) {
          int f = mf * 4 + nf;
          acc_i[f] = __builtin_amdgcn_mfma_f32_16x16x32_bf16(fa[mf], bi, acc_i[f], 0, 0, 0);
          acc_h[f] = __builtin_amdgcn_mfma_f32_16x16x32_bf16(fh[mf], bh, acc_h[f], 0, 0, 0);
        }
      }
    }

    if (gate < 2) {
#pragma unroll
      for (int mf = 0; mf < 2; ++mf)
#pragma unroll
        for (int nf = 0; nf < 4; ++nf) {
          int f = mf * 4 + nf;
          int col = wcol0 + nf * 16 + l15;
          float bi = bih[gate * 128 + col], bh = bhh[gate * 128 + col];
#pragma unroll
          for (int r = 0; r < 4; ++r) {
            float v = acc_i[f][r] + acc_h[f][r] + bi + bh;
            float sg = 1.f / (1.f + __expf(-v));
            if (gate == 0) rr[f][r] = sg;
            else zz[f][r] = sg;
          }
        }
    } else {
#pragma unroll
      for (int mf = 0; mf < 2; ++mf)
#pragma unroll
        for (int r = 0; r < 4; ++r) {
          int grow = bm + wrow0 + mf * 16 + lhi * 4 + r;
          if (grow >= NN) continue;
#pragma unroll
          for (int nf = 0; nf < 4; ++nf) {
            int f = mf * 4 + nf;
            int col = wcol0 + nf * 16 + l15;
            float in_ = acc_i[f][r] + bih[256 + col];
            float hn = acc_h[f][r] + bhh[256 + col];
            float x = in_ + rr[f][r] * hn;
            float e = __expf(-2.f * x);
            float n = (1.f - e) / (1.f + e);
            float z = zz[f][r];
            float ho = hf[(size_t)grow * 128 + col];
            float hv = (1.f - z) * n + z * ho;
            hf[(size_t)grow * 128 + col] = hv;
            hbf[(size_t)grow * 128 + col] = f2bf(hv);
          }
        }
    }
  }
}

// ---------- fp32 GEMM for h0 (B streamed from cache) ----------
template <int KD>
__global__ void __launch_bounds__(256)
gemm_cacheB(const float* __restrict__ X, const int* __restrict__ rowidx,
            const float* __restrict__ B, int ldb, const float* __restrict__ bias,
            float* __restrict__ C, float* __restrict__ C2, int M) {
  __shared__ float xs[KD * 64];
  constexpr int KC = KD / 4;
  const int tid = threadIdx.x;
  const int bm = blockIdx.x * 64;

  for (int idx = tid; idx < 64 * KC; idx += 256) {
    int m = idx / KC, c = idx - m * KC;
    int gm = bm + m;
    float4 v = make_float4(0.f, 0.f, 0.f, 0.f);
    if (gm < M) {
      int r = rowidx ? rowidx[gm] : gm;
      v = *(const float4*)(X + (size_t)r * KD + 4 * c);
    }
    int k0 = 4 * c;
    xs[(k0 + 0) * 64 + ((((m >> 2) ^ ((k0 + 0) & 15)) << 2) | (m & 3))] = v.x;
    xs[(k0 + 1) * 64 + ((((m >> 2) ^ ((k0 + 1) & 15)) << 2) | (m & 3))] = v.y;
    xs[(k0 + 2) * 64 + ((((m >> 2) ^ ((k0 + 2) & 15)) << 2) | (m & 3))] = v.z;
    xs[(k0 + 3) * 64 + ((((m >> 2) ^ ((k0 + 3) & 15)) << 2) | (m & 3))] = v.w;
  }
  __syncthreads();

  const int tx = tid & 15, ty = tid >> 4;
  float acc[4][8] = {};
#pragma unroll 4
  for (int k = 0; k < KD; ++k) {
    float4 a = *(float4*)(xs + k * 64 + ((ty ^ (k & 15)) << 2));
    float4 b0 = *(const float4*)(B + (size_t)k * ldb + 4 * tx);
    float4 b1 = *(const float4*)(B + (size_t)k * ldb + 64 + 4 * tx);
    float av[4] = {a.x, a.y, a.z, a.w};
    float bv[8] = {b0.x, b0.y, b0.z, b0.w, b1.x, b1.y, b1.z, b1.w};
#pragma unroll
    for (int i = 0; i < 4; ++i)
#pragma unroll
      for (int j = 0; j < 8; ++j) acc[i][j] += av[i] * bv[j];
  }

#pragma unroll
  for (int i = 0; i < 4; ++i) {
    int gm = bm + 4 * ty + i;
    if (gm >= M) continue;
    float4 o0, o1;
    o0.x = acc[i][0] + bias[4 * tx + 0];
    o0.y = acc[i][1] + bias[4 * tx + 1];
    o0.z = acc[i][2] + bias[4 * tx + 2];
    o0.w = acc[i][3] + bias[4 * tx + 3];
    o1.x = acc[i][4] + bias[64 + 4 * tx + 0];
    o1.y = acc[i][5] + bias[64 + 4 * tx + 1];
    o1.z = acc[i][6] + bias[64 + 4 * tx + 2];
    o1.w = acc[i][7] + bias[64 + 4 * tx + 3];
    *(float4*)(C + (size_t)gm * 128 + 4 * tx) = o0;
    *(float4*)(C + (size_t)gm * 128 + 64 + 4 * tx) = o1;
    if (C2) {
      *(float4*)(C2 + (size_t)gm * 128 + 4 * tx) = o0;
      *(float4*)(C2 + (size_t)gm * 128 + 64 + 4 * tx) = o1;
    }
  }
}

// ---------- CSR build keyed by b = et*NN + dst ----------
__global__ void count3_k(const int* __restrict__ dst, const int* __restrict__ et,
                         int* __restrict__ deg3) {
  int e = blockIdx.x * 256 + threadIdx.x;
  if (e < NE) atomicAdd(&deg3[et[e] * NN + dst[e]], 1);
}
__global__ void scan1(const int* __restrict__ deg, int* __restrict__ rowst,
                      int* __restrict__ csum, int L) {
  __shared__ int s[256];
  int base = blockIdx.x * 1024;
  int tid = threadIdx.x;
  int v[4], pre[4];
  int run = 0;
#pragma unroll
  for (int j = 0; j < 4; ++j) {
    int idx = base + tid * 4 + j;
    v[j] = (idx < L) ? deg[idx] : 0;
    pre[j] = run;
    run += v[j];
  }
  s[tid] = run;
  __syncthreads();
  for (int off = 1; off < 256; off <<= 1) {
    int t = (tid >= off) ? s[tid - off] : 0;
    __syncthreads();
    s[tid] += t;
    __syncthreads();
  }
  int excl = (tid == 0) ? 0 : s[tid - 1];
#pragma unroll
  for (int j = 0; j < 4; ++j) {
    int idx = base + tid * 4 + j;
    if (idx < L) rowst[idx] = excl + pre[j];
  }
  if (tid == 255) csum[blockIdx.x] = s[255];
}
__global__ void scan2(int* csum, int nch) {
  if (threadIdx.x == 0 && blockIdx.x == 0) {
    int run = 0;
    for (int i = 0; i < nch; ++i) { int t = csum[i]; csum[i] = run; run += t; }
  }
}
__global__ void scan3(int* rowst, const int* __restrict__ csum, int L) {
  int idx = blockIdx.x * 256 + threadIdx.x;
  if (idx < L) rowst[idx] += csum[idx >> 10];
}
__global__ void set_last(int* rowst) { rowst[3 * NN] = NE; }
__global__ void fill3_k(const int* __restrict__ src, const int* __restrict__ dst,
                        const int* __restrict__ et, const int* __restrict__ rowst3,
                        int* __restrict__ cursor3, int* __restrict__ payload) {
  int e = blockIdx.x * 256 + threadIdx.x;
  if (e >= NE) return;
  int b3 = et[e] * NN + dst[e];
  int pos = rowst3[b3] + atomicAdd(&cursor3[b3], 1);
  payload[pos] = src[e] | ((dst[e] & 63) << 17);
}

// ---------- misc ----------
__global__ void transpose_w(const float* __restrict__ W, float* __restrict__ WT,
                            int J, int Kd) {
  int idx = blockIdx.x * 256 + threadIdx.x;
  if (idx >= J * Kd) return;
  int j = idx / Kd, k = idx - j * Kd;
  WT[(size_t)k * J + j] = W[idx];
}

__global__ void conv_bf16v(const float* __restrict__ s, unsigned short* __restrict__ d,
                           int n4) {
  int i = blockIdx.x * 256 + threadIdx.x;
  if (i >= n4) return;
  float4 v = *(const float4*)(s + 4 * (size_t)i);
  unsigned lo = (unsigned)f2bf(v.x) | ((unsigned)f2bf(v.y) << 16);
  unsigned hi = (unsigned)f2bf(v.z) | ((unsigned)f2bf(v.w) << 16);
  *(unsigned*)(d + 4 * (size_t)i) = lo;
  *(unsigned*)(d + 4 * (size_t)i + 2) = hi;
}

__global__ void __launch_bounds__(256)
gate_k(const float* __restrict__ h, const float* __restrict__ h0,
       const float* __restrict__ Wg, const float* __restrict__ bg,
       float* __restrict__ gate) {
  int wid = threadIdx.x >> 6, lane = threadIdx.x & 63;
  int n = blockIdx.x * 4 + wid;
  if (n >= NN) return;
  float2 hv = *(const float2*)(h + (size_t)n * 128 + 2 * lane);
  float2 h0v = *(const float2*)(h0 + (size_t)n * 128 + 2 * lane);
  float p = hv.x * Wg[2 * lane] + hv.y * Wg[2 * lane + 1] +
            h0v.x * Wg[128 + 2 * lane] + h0v.y * Wg[128 + 2 * lane + 1];
  p = wave_sum(p);
  if (lane == 0) gate[n] = p + bg[0];
}

__global__ void bounds_k(const int* __restrict__ gid, int* __restrict__ bound) {
  int g = threadIdx.x;
  if (g > NG) return;
  int lo = 0, hi = NN;
  while (lo < hi) {
    int mid = (lo + hi) >> 1;
    if (gid[mid] < g) lo = mid + 1; else hi = mid;
  }
  bound[g] = lo;
}

__global__ void __launch_bounds__(256)
pool_k(const float* __restrict__ h, const float* __restrict__ h0,
       const float* __restrict__ gate, const int* __restrict__ bound,
       const float* __restrict__ Wout, const float* __restrict__ bout,
       float* __restrict__ out) {
  int g = blockIdx.x;
  int s = bound[g], e = bound[g + 1];
  __shared__ float sred[4];
  __shared__ float sbc[2];
  __shared__ float facc[1024];
  int tid = threadIdx.x, wid = tid >> 6, lane = tid & 63;
  if (s >= e) { if (tid == 0) out[g] = bout[0]; return; }

  float mx = -3.4e38f;
  for (int i = s + tid; i < e; i += 256) mx = fmaxf(mx, gate[i]);
  mx = wave_max(mx);
  if (lane == 0) sred[wid] = mx;
  __syncthreads();
  if (tid == 0) sbc[0] = fmaxf(fmaxf(sred[0], sred[1]), fmaxf(sred[2], sred[3]));
  __syncthreads();
  float mglob = sbc[0];

  float ss = 0.f;
  for (int i = s + tid; i < e; i += 256) ss += expf(gate[i] - mglob);
  ss = wave_sum(ss);
  if (lane == 0) sred[wid] = ss;
  __syncthreads();
  if (tid == 0) sbc[1] = sred[0] + sred[1] + sred[2] + sred[3];
  __syncthreads();
  float S = sbc[1];

  float a0 = 0.f, a1 = 0.f, a2 = 0.f, a3 = 0.f;
  for (int n = s + wid; n < e; n += 4) {
    float alpha = expf(gate[n] - mglob) / S;
    const float* p = (lane < 32) ? (h + (size_t)n * 128 + 4 * lane)
                                 : (h0 + (size_t)n * 128 + 4 * (lane - 32));
    float4 v = *(const float4*)p;
    a0 += alpha * v.x; a1 += alpha * v.y; a2 += alpha * v.z; a3 += alpha * v.w;
  }
  facc[wid * 256 + 4 * lane + 0] = a0;
  facc[wid * 256 + 4 * lane + 1] = a1;
  facc[wid * 256 + 4 * lane + 2] = a2;
  facc[wid * 256 + 4 * lane + 3] = a3;
  __syncthreads();
  float rsum = facc[tid] + facc[256 + tid] + facc[512 + tid] + facc[768 + tid];
  float val = rsum * Wout[tid];
  val = wave_sum(val);
  if (lane == 0) sred[wid] = val;
  __syncthreads();
  if (tid == 0) out[g] = sred[0] + sred[1] + sred[2] + sred[3] + bout[0];
}

// ---------- host ----------
extern "C" void kernel_launch(void* const* d_in, const int* in_sizes, int n_in,
                              void* d_out, int out_size, void* d_ws, size_t ws_size,
                              hipStream_t stream) {
  (void)in_sizes; (void)n_in; (void)out_size; (void)ws_size;
  const int* type_ids = (const int*)d_in[0];
  const int* src      = (const int*)d_in[1];
  const int* dst      = (const int*)d_in[2];
  const int* etypes   = (const int*)d_in[3];
  const int* gid      = (const int*)d_in[4];
  const float* embed  = (const float*)d_in[5];
  const float* W_red  = (const float*)d_in[6];
  const float* b_red  = (const float*)d_in[7];
  const float* W_msg  = (const float*)d_in[8];
  const float* b_msg  = (const float*)d_in[9];
  const float* W_ih   = (const float*)d_in[10];
  const float* b_ih   = (const float*)d_in[11];
  const float* W_hh   = (const float*)d_in[12];
  const float* b_hh   = (const float*)d_in[13];
  const float* W_gate = (const float*)d_in[14];
  const float* b_gate = (const float*)d_in[15];
  const float* W_out  = (const float*)d_in[16];
  const float* b_out  = (const float*)d_in[17];

  char* p = (char*)d_ws;
  auto take = [&](size_t nb) { char* r = p; p += (nb + 255) & ~(size_t)255; return r; };
  float* hf            = (float*)take((size_t)NN * 128 * sizeof(float));
  float* h0b           = (float*)take((size_t)NN * 128 * sizeof(float));
  float* af            = (float*)take((size_t)NN * 128 * sizeof(float));
  unsigned short* hbf  = (unsigned short*)take((size_t)NN * 128 * 2);
  unsigned short* WmsgF = (unsigned short*)take(49152 * 2);
  unsigned short* WihF  = (unsigned short*)take(49152 * 2);
  unsigned short* WhhF  = (unsigned short*)take(49152 * 2);
  float* WredT = (float*)take(64 * 128 * sizeof(float));
  float* gateb = (float*)take((size_t)NN * sizeof(float));
  int* deg3    = (int*)take((size_t)2 * 3 * NN * sizeof(int));
  int* cursor3 = deg3 + 3 * NN;
  int* rowst3x = (int*)take(((size_t)3 * NN + 1) * sizeof(int));
  int* payload = (int*)take((size_t)NE * sizeof(int));
  int* csum    = (int*)take(2048);
  int* bound   = (int*)take(512);

  // weight prep: k-major fp32 for h0, fragment-major bf16 for MFMA kernels
  transpose_w<<<(128 * 64 + 255) / 256, 256, 0, stream>>>(W_red, WredT, 128, 64);
  pack_fragB<<<24, 256, 0, stream>>>(W_msg, WmsgF);
  pack_fragB<<<24, 256, 0, stream>>>(W_ih, WihF);
  pack_fragB<<<24, 256, 0, stream>>>(W_hh, WhhF);

  // CSR keyed by (etype, dst)
  const int L3 = 3 * NN;
  hipMemsetAsync(deg3, 0, (size_t)2 * L3 * sizeof(int), stream);
  count3_k<<<(NE + 255) / 256, 256, 0, stream>>>(dst, etypes, deg3);
  int nch = (L3 + 1023) / 1024;
  scan1<<<nch, 256, 0, stream>>>(deg3, rowst3x, csum, L3);
  scan2<<<1, 64, 0, stream>>>(csum, nch);
  scan3<<<(L3 + 255) / 256, 256, 0, stream>>>(rowst3x, csum, L3);
  set_last<<<1, 1, 0, stream>>>(rowst3x);
  fill3_k<<<(NE + 255) / 256, 256, 0, stream>>>(src, dst, etypes, rowst3x, cursor3, payload);

  // h0 = embed[type_ids] @ W_red^T + b_red ; hf = h0 ; hbf shadow
  gemm_cacheB<64><<<(NN + 63) / 64, 256, 0, stream>>>(
      embed, type_ids, WredT, 128, b_red, h0b, hf, NN);
  conv_bf16v<<<((NN * 128 / 4) + 255) / 256, 256, 0, stream>>>(hf, hbf, NN * 128 / 4);

  const int nblk = (NN + 63) / 64;
  for (int s6 = 0; s6 < 6; ++s6) {
    msg_mfma3<<<nblk, 256, 0, stream>>>((const unsigned*)hbf, rowst3x, payload,
                                        WmsgF, b_msg, af);
    gru_mfma3<<<nblk, 256, 0, stream>>>(hf, hbf, af, WihF, WhhF, b_ih, b_hh);
  }

  gate_k<<<(NN + 3) / 4, 256, 0, stream>>>(hf, h0b, W_gate, b_gate, gateb);
  bounds_k<<<1, 128, 0, stream>>>(gid, bound);
  pool_k<<<NG, 256, 0, stream>>>(hf, h0b, gateb, bound, W_out, b_out, (float*)d_out);
}

// Round 6
// 3438.050 us; speedup vs baseline: 2.5736x; 1.0318x over previous
//
#include <hip/hip_runtime.h>

#define NN 100000
#define NE 1600000
#define NG 64

typedef __attribute__((ext_vector_type(8))) short bf16x8;
typedef __attribute__((ext_vector_type(4))) float f32x4;

__device__ __forceinline__ unsigned short f2bf(float f) {
  unsigned u = __float_as_uint(f);
  unsigned r = u + 0x7FFFu + ((u >> 16) & 1u);
  return (unsigned short)(r >> 16);
}
__device__ __forceinline__ float bf2f(unsigned u16) {
  return __uint_as_float(u16 << 16);
}

__device__ __forceinline__ float wave_sum(float v) {
#pragma unroll
  for (int off = 32; off; off >>= 1) v += __shfl_down(v, off, 64);
  return v;
}
__device__ __forceinline__ float wave_max(float v) {
#pragma unroll
  for (int off = 32; off; off >>= 1) v = fmaxf(v, __shfl_down(v, off, 64));
  return v;
}

// read one MFMA fragment (16B) from a swizzled [rows][256B] LDS tile image
__device__ __forceinline__ bf16x8 frag_ld(const char* base, int row, int kbyte) {
  return *(const bf16x8*)(base + row * 256 + (kbyte ^ ((row & 7) << 4)));
}

// ---------------- fragment-major weight repack ----------------
__global__ void pack_fragB(const float* __restrict__ W, unsigned short* __restrict__ WF) {
  int idx = blockIdx.x * 256 + threadIdx.x;
  if (idx >= 3 * 4 * 8 * 64) return;
  int lane = idx & 63;
  int c = (idx >> 6) & 7;
  int ks = (idx >> 9) & 3;
  int g = idx >> 11;
  int col = c * 16 + (lane & 15);
  int k0 = ks * 32 + (lane >> 4) * 8;
  const float* src = W + ((size_t)g * 128 + col) * 128 + k0;
  bf16x8 o;
#pragma unroll
  for (int j = 0; j < 8; ++j) o[j] = (short)f2bf(src[j]);
  *(bf16x8*)(WF + (size_t)idx * 8) = o;
}

// ---------------- fused message pass v4: reg-double-buffered gather + MFMA ----------------
// CSR keyed b = et*NN + dst; payload = src | ((dst&63)<<17)

#define MSG_ISSUE(V, R, BB)                                                \
  do {                                                                     \
    int _base = (BB) * 8;                                                  \
    _Pragma("unroll") for (int j = 0; j < 8; ++j) {                        \
      int _idx = _base + j;                                                \
      if (_idx < c64) {                                                    \
        int _p = __shfl(pv, _idx, 64);                                     \
        R[j] = _p >> 17;                                                   \
        V[j] = hbf32[(size_t)(_p & 0x1FFFF) * 64 + lane];                  \
      }                                                                    \
    }                                                                      \
  } while (0)

#define MSG_CONSUME(V, R, BB)                                              \
  do {                                                                     \
    int _base = (BB) * 8;                                                  \
    _Pragma("unroll") for (int j = 0; j < 8; ++j) {                        \
      if (_base + j < c64) {                                               \
        int _row = R[j];                                                   \
        if (_row != cur) {                                                 \
          if (cur >= 0)                                                    \
            *(float2*)&accf[cur * 132 + 2 * lane] = make_float2(sx, sy);   \
          cur = _row;                                                      \
          sx = 0.f;                                                        \
          sy = 0.f;                                                        \
        }                                                                  \
        unsigned _v = V[j];                                                \
        sx += bf2f(_v & 0xffffu);                                          \
        sy += bf2f(_v >> 16);                                              \
      }                                                                    \
    }                                                                      \
  } while (0)

__global__ void __launch_bounds__(256)
msg_mfma4(const unsigned* __restrict__ hbf32, const int* __restrict__ rowst,
          const int* __restrict__ payload, const unsigned short* __restrict__ WmsgF,
          const float* __restrict__ bmsg, unsigned short* __restrict__ abf) {
  __shared__ float accf[64 * 132];  // padded fp32 accumulator tile
  const int tid = threadIdx.x, lane = tid & 63, wid = tid >> 6;
  const int l15 = lane & 15, lhi = lane >> 4;
  const int bm = blockIdx.x * 64;
  const int wrow0 = (wid >> 1) * 32, wcol0 = (wid & 1) * 64;
  const int nend = min(bm + 64, NN);

  f32x4 acc[8];
#pragma unroll
  for (int f = 0; f < 8; ++f)
#pragma unroll
    for (int r = 0; r < 4; ++r) acc[f][r] = 0.f;

  for (int et = 0; et < 3; ++et) {
    __syncthreads();  // prior MFMA phase done reading accf
    for (int i = tid; i < 64 * 132; i += 256) accf[i] = 0.f;
    __syncthreads();

    int n0 = bm + wid * 16;
    if (n0 < nend) {
      int n1 = min(n0 + 16, nend);
      const int ws = rowst[et * NN + n0];
      const int we = rowst[et * NN + n1];
      float sx = 0.f, sy = 0.f;
      int cur = -1;
      for (int cb = ws; cb < we; cb += 64) {
        const int c64 = min(64, we - cb);
        int pv = (lane < c64) ? payload[cb + lane] : 0;
        unsigned va[8], vb[8];
        int ra[8], rb[8];
        const int nb = (c64 + 7) >> 3;
        MSG_ISSUE(va, ra, 0);
        int b = 0;
        while (b < nb) {
          MSG_ISSUE(vb, rb, b + 1);
          MSG_CONSUME(va, ra, b);
          ++b;
          if (b >= nb) break;
          MSG_ISSUE(va, ra, b + 1);
          MSG_CONSUME(vb, rb, b);
          ++b;
        }
      }
      if (cur >= 0) *(float2*)&accf[cur * 132 + 2 * lane] = make_float2(sx, sy);
    }
    __syncthreads();

    // MFMA accumulate for this etype; B fragments coalesced (fragment-major)
#pragma unroll
    for (int ks = 0; ks < 4; ++ks) {
      bf16x8 afr[2];
#pragma unroll
      for (int mf = 0; mf < 2; ++mf) {
        int row = wrow0 + mf * 16 + l15;
        const float* pr = accf + row * 132 + ks * 32 + lhi * 8;
        f32x4 x0 = *(const f32x4*)pr;
        f32x4 x1 = *(const f32x4*)(pr + 4);
#pragma unroll
        for (int j = 0; j < 4; ++j) {
          afr[mf][j] = (short)f2bf(x0[j]);
          afr[mf][4 + j] = (short)f2bf(x1[j]);
        }
      }
#pragma unroll
      for (int nf = 0; nf < 4; ++nf) {
        bf16x8 bfr = *(const bf16x8*)(WmsgF +
            (((size_t)(et * 4 + ks) * 8 + (wcol0 >> 4) + nf) * 64 + lane) * 8);
#pragma unroll
        for (int mf = 0; mf < 2; ++mf)
          acc[mf * 4 + nf] = __builtin_amdgcn_mfma_f32_16x16x32_bf16(
              afr[mf], bfr, acc[mf * 4 + nf], 0, 0, 0);
      }
    }
  }

  // epilogue: deg-weighted bias (degs from rowst diffs), store bf16 a
#pragma unroll
  for (int mf = 0; mf < 2; ++mf)
#pragma unroll
    for (int r = 0; r < 4; ++r) {
      int grow = bm + wrow0 + mf * 16 + lhi * 4 + r;
      if (grow >= NN) continue;
      float d0 = (float)(rowst[grow + 1] - rowst[grow]);
      float d1 = (float)(rowst[NN + grow + 1] - rowst[NN + grow]);
      float d2 = (float)(rowst[2 * NN + grow + 1] - rowst[2 * NN + grow]);
#pragma unroll
      for (int nf = 0; nf < 4; ++nf) {
        int col = wcol0 + nf * 16 + l15;
        float v = acc[mf * 4 + nf][r] + d0 * bmsg[col] + d1 * bmsg[128 + col] +
                  d2 * bmsg[256 + col];
        abf[(size_t)grow * 128 + col] = f2bf(v);
      }
    }
}

// ---------------- fused GRU v4: bf16 A-tiles staged raw from abf/hbf ----------------
__global__ void __launch_bounds__(256)
gru_mfma4(float* __restrict__ hf, unsigned short* __restrict__ hbf,
          const unsigned short* __restrict__ abf, const unsigned short* __restrict__ WihF,
          const unsigned short* __restrict__ WhhF, const float* __restrict__ bih,
          const float* __restrict__ bhh) {
  __shared__ char Aa[16384];
  __shared__ char Ah[16384];
  const int tid = threadIdx.x, lane = tid & 63, wid = tid >> 6;
  const int l15 = lane & 15, lhi = lane >> 4;
  const int bm = blockIdx.x * 64;
  const int wrow0 = (wid >> 1) * 32, wcol0 = (wid & 1) * 64;

  for (int idx = tid; idx < 1024; idx += 256) {
    int row = idx >> 4, o = (idx & 15) << 4;
    int gr = bm + row;
    uint4 va = make_uint4(0, 0, 0, 0), vh = make_uint4(0, 0, 0, 0);
    if (gr < NN) {
      va = *(const uint4*)((const char*)abf + (size_t)gr * 256 + o);
      vh = *(const uint4*)((const char*)hbf + (size_t)gr * 256 + o);
    }
    int so = row * 256 + (o ^ ((row & 7) << 4));
    *(uint4*)(Aa + so) = va;
    *(uint4*)(Ah + so) = vh;
  }
  __syncthreads();

  f32x4 rr[8], zz[8];
  for (int gate = 0; gate < 3; ++gate) {
    f32x4 acc_i[8], acc_h[8];
#pragma unroll
    for (int f = 0; f < 8; ++f)
#pragma unroll
      for (int r = 0; r < 4; ++r) { acc_i[f][r] = 0.f; acc_h[f][r] = 0.f; }

#pragma unroll
    for (int ks = 0; ks < 4; ++ks) {
      int kb = ks * 64 + lhi * 16;
      bf16x8 fa[2], fh[2];
#pragma unroll
      for (int mf = 0; mf < 2; ++mf) {
        int row = wrow0 + mf * 16 + l15;
        fa[mf] = frag_ld(Aa, row, kb);
        fh[mf] = frag_ld(Ah, row, kb);
      }
#pragma unroll
      for (int nf = 0; nf < 4; ++nf) {
        size_t fidx = (((size_t)(gate * 4 + ks) * 8 + (wcol0 >> 4) + nf) * 64 + lane) * 8;
        bf16x8 bi = *(const bf16x8*)(WihF + fidx);
        bf16x8 bh = *(const bf16x8*)(WhhF + fidx);
#pragma unroll
        for (int mf = 0; mf < 2; ++mf) {
          int f = mf * 4 + nf;
          acc_i[f] = __builtin_amdgcn_mfma_f32_16x16x32_bf16(fa[mf], bi, acc_i[f], 0, 0, 0);
          acc_h[f] = __builtin_amdgcn_mfma_f32_16x16x32_bf16(fh[mf], bh, acc_h[f], 0, 0, 0);
        }
      }
    }

    if (gate < 2) {
#pragma unroll
      for (int mf = 0; mf < 2; ++mf)
#pragma unroll
        for (int nf = 0; nf < 4; ++nf) {
          int f = mf * 4 + nf;
          int col = wcol0 + nf * 16 + l15;
          float bi = bih[gate * 128 + col], bh = bhh[gate * 128 + col];
#pragma unroll
          for (int r = 0; r < 4; ++r) {
            float v = acc_i[f][r] + acc_h[f][r] + bi + bh;
            float sg = 1.f / (1.f + __expf(-v));
            if (gate == 0) rr[f][r] = sg;
            else zz[f][r] = sg;
          }
        }
    } else {
#pragma unroll
      for (int mf = 0; mf < 2; ++mf)
#pragma unroll
        for (int r = 0; r < 4; ++r) {
          int grow = bm + wrow0 + mf * 16 + lhi * 4 + r;
          if (grow >= NN) continue;
#pragma unroll
          for (int nf = 0; nf < 4; ++nf) {
            int f = mf * 4 + nf;
            int col = wcol0 + nf * 16 + l15;
            float in_ = acc_i[f][r] + bih[256 + col];
            float hn = acc_h[f][r] + bhh[256 + col];
            float x = in_ + rr[f][r] * hn;
            float e = __expf(-2.f * x);
            float n = (1.f - e) / (1.f + e);
            float z = zz[f][r];
            float ho = hf[(size_t)grow * 128 + col];
            float hv = (1.f - z) * n + z * ho;
            hf[(size_t)grow * 128 + col] = hv;
            hbf[(size_t)grow * 128 + col] = f2bf(hv);
          }
        }
    }
  }
}

// ---------- fp32 GEMM for h0 (B streamed from cache) ----------
template <int KD>
__global__ void __launch_bounds__(256)
gemm_cacheB(const float* __restrict__ X, const int* __restrict__ rowidx,
            const float* __restrict__ B, int ldb, const float* __restrict__ bias,
            float* __restrict__ C, float* __restrict__ C2, int M) {
  __shared__ float xs[KD * 64];
  constexpr int KC = KD / 4;
  const int tid = threadIdx.x;
  const int bm = blockIdx.x * 64;

  for (int idx = tid; idx < 64 * KC; idx += 256) {
    int m = idx / KC, c = idx - m * KC;
    int gm = bm + m;
    float4 v = make_float4(0.f, 0.f, 0.f, 0.f);
    if (gm < M) {
      int r = rowidx ? rowidx[gm] : gm;
      v = *(const float4*)(X + (size_t)r * KD + 4 * c);
    }
    int k0 = 4 * c;
    xs[(k0 + 0) * 64 + ((((m >> 2) ^ ((k0 + 0) & 15)) << 2) | (m & 3))] = v.x;
    xs[(k0 + 1) * 64 + ((((m >> 2) ^ ((k0 + 1) & 15)) << 2) | (m & 3))] = v.y;
    xs[(k0 + 2) * 64 + ((((m >> 2) ^ ((k0 + 2) & 15)) << 2) | (m & 3))] = v.z;
    xs[(k0 + 3) * 64 + ((((m >> 2) ^ ((k0 + 3) & 15)) << 2) | (m & 3))] = v.w;
  }
  __syncthreads();

  const int tx = tid & 15, ty = tid >> 4;
  float acc[4][8] = {};
#pragma unroll 4
  for (int k = 0; k < KD; ++k) {
    float4 a = *(float4*)(xs + k * 64 + ((ty ^ (k & 15)) << 2));
    float4 b0 = *(const float4*)(B + (size_t)k * ldb + 4 * tx);
    float4 b1 = *(const float4*)(B + (size_t)k * ldb + 64 + 4 * tx);
    float av[4] = {a.x, a.y, a.z, a.w};
    float bv[8] = {b0.x, b0.y, b0.z, b0.w, b1.x, b1.y, b1.z, b1.w};
#pragma unroll
    for (int i = 0; i < 4; ++i)
#pragma unroll
      for (int j = 0; j < 8; ++j) acc[i][j] += av[i] * bv[j];
  }

#pragma unroll
  for (int i = 0; i < 4; ++i) {
    int gm = bm + 4 * ty + i;
    if (gm >= M) continue;
    float4 o0, o1;
    o0.x = acc[i][0] + bias[4 * tx + 0];
    o0.y = acc[i][1] + bias[4 * tx + 1];
    o0.z = acc[i][2] + bias[4 * tx + 2];
    o0.w = acc[i][3] + bias[4 * tx + 3];
    o1.x = acc[i][4] + bias[64 + 4 * tx + 0];
    o1.y = acc[i][5] + bias[64 + 4 * tx + 1];
    o1.z = acc[i][6] + bias[64 + 4 * tx + 2];
    o1.w = acc[i][7] + bias[64 + 4 * tx + 3];
    *(float4*)(C + (size_t)gm * 128 + 4 * tx) = o0;
    *(float4*)(C + (size_t)gm * 128 + 64 + 4 * tx) = o1;
    if (C2) {
      *(float4*)(C2 + (size_t)gm * 128 + 4 * tx) = o0;
      *(float4*)(C2 + (size_t)gm * 128 + 64 + 4 * tx) = o1;
    }
  }
}

// ---------- CSR build keyed by b = et*NN + dst ----------
__global__ void count3_k(const int* __restrict__ dst, const int* __restrict__ et,
                         int* __restrict__ deg3) {
  int e = blockIdx.x * 256 + threadIdx.x;
  if (e < NE) atomicAdd(&deg3[et[e] * NN + dst[e]], 1);
}
__global__ void scan1(const int* __restrict__ deg, int* __restrict__ rowst,
                      int* __restrict__ csum, int L) {
  __shared__ int s[256];
  int base = blockIdx.x * 1024;
  int tid = threadIdx.x;
  int v[4], pre[4];
  int run = 0;
#pragma unroll
  for (int j = 0; j < 4; ++j) {
    int idx = base + tid * 4 + j;
    v[j] = (idx < L) ? deg[idx] : 0;
    pre[j] = run;
    run += v[j];
  }
  s[tid] = run;
  __syncthreads();
  for (int off = 1; off < 256; off <<= 1) {
    int t = (tid >= off) ? s[tid - off] : 0;
    __syncthreads();
    s[tid] += t;
    __syncthreads();
  }
  int excl = (tid == 0) ? 0 : s[tid - 1];
#pragma unroll
  for (int j = 0; j < 4; ++j) {
    int idx = base + tid * 4 + j;
    if (idx < L) rowst[idx] = excl + pre[j];
  }
  if (tid == 255) csum[blockIdx.x] = s[255];
}
__global__ void scan2(int* csum, int nch) {
  if (threadIdx.x == 0 && blockIdx.x == 0) {
    int run = 0;
    for (int i = 0; i < nch; ++i) { int t = csum[i]; csum[i] = run; run += t; }
  }
}
__global__ void scan3(int* rowst, const int* __restrict__ csum, int L) {
  int idx = blockIdx.x * 256 + threadIdx.x;
  if (idx < L) rowst[idx] += csum[idx >> 10];
}
__global__ void set_last(int* rowst) { rowst[3 * NN] = NE; }
__global__ void fill3_k(const int* __restrict__ src, const int* __restrict__ dst,
                        const int* __restrict__ et, const int* __restrict__ rowst3,
                        int* __restrict__ cursor3, int* __restrict__ payload) {
  int e = blockIdx.x * 256 + threadIdx.x;
  if (e >= NE) return;
  int b3 = et[e] * NN + dst[e];
  int pos = rowst3[b3] + atomicAdd(&cursor3[b3], 1);
  payload[pos] = src[e] | ((dst[e] & 63) << 17);
}

// ---------- misc ----------
__global__ void transpose_w(const float* __restrict__ W, float* __restrict__ WT,
                            int J, int Kd) {
  int idx = blockIdx.x * 256 + threadIdx.x;
  if (idx >= J * Kd) return;
  int j = idx / Kd, k = idx - j * Kd;
  WT[(size_t)k * J + j] = W[idx];
}

__global__ void conv_bf16v(const float* __restrict__ s, unsigned short* __restrict__ d,
                           int n4) {
  int i = blockIdx.x * 256 + threadIdx.x;
  if (i >= n4) return;
  float4 v = *(const float4*)(s + 4 * (size_t)i);
  unsigned lo = (unsigned)f2bf(v.x) | ((unsigned)f2bf(v.y) << 16);
  unsigned hi = (unsigned)f2bf(v.z) | ((unsigned)f2bf(v.w) << 16);
  *(unsigned*)(d + 4 * (size_t)i) = lo;
  *(unsigned*)(d + 4 * (size_t)i + 2) = hi;
}

__global__ void __launch_bounds__(256)
gate_k(const float* __restrict__ h, const float* __restrict__ h0,
       const float* __restrict__ Wg, const float* __restrict__ bg,
       float* __restrict__ gate) {
  int wid = threadIdx.x >> 6, lane = threadIdx.x & 63;
  int n = blockIdx.x * 4 + wid;
  if (n >= NN) return;
  float2 hv = *(const float2*)(h + (size_t)n * 128 + 2 * lane);
  float2 h0v = *(const float2*)(h0 + (size_t)n * 128 + 2 * lane);
  float p = hv.x * Wg[2 * lane] + hv.y * Wg[2 * lane + 1] +
            h0v.x * Wg[128 + 2 * lane] + h0v.y * Wg[128 + 2 * lane + 1];
  p = wave_sum(p);
  if (lane == 0) gate[n] = p + bg[0];
}

__global__ void bounds_k(const int* __restrict__ gid, int* __restrict__ bound) {
  int g = threadIdx.x;
  if (g > NG) return;
  int lo = 0, hi = NN;
  while (lo < hi) {
    int mid = (lo + hi) >> 1;
    if (gid[mid] < g) lo = mid + 1; else hi = mid;
  }
  bound[g] = lo;
}

__global__ void __launch_bounds__(256)
pool_k(const float* __restrict__ h, const float* __restrict__ h0,
       const float* __restrict__ gate, const int* __restrict__ bound,
       const float* __restrict__ Wout, const float* __restrict__ bout,
       float* __restrict__ out) {
  int g = blockIdx.x;
  int s = bound[g], e = bound[g + 1];
  __shared__ float sred[4];
  __shared__ float sbc[2];
  __shared__ float facc[1024];
  int tid = threadIdx.x, wid = tid >> 6, lane = tid & 63;
  if (s >= e) { if (tid == 0) out[g] = bout[0]; return; }

  float mx = -3.4e38f;
  for (int i = s + tid; i < e; i += 256) mx = fmaxf(mx, gate[i]);
  mx = wave_max(mx);
  if (lane == 0) sred[wid] = mx;
  __syncthreads();
  if (tid == 0) sbc[0] = fmaxf(fmaxf(sred[0], sred[1]), fmaxf(sred[2], sred[3]));
  __syncthreads();
  float mglob = sbc[0];

  float ss = 0.f;
  for (int i = s + tid; i < e; i += 256) ss += expf(gate[i] - mglob);
  ss = wave_sum(ss);
  if (lane == 0) sred[wid] = ss;
  __syncthreads();
  if (tid == 0) sbc[1] = sred[0] + sred[1] + sred[2] + sred[3];
  __syncthreads();
  float S = sbc[1];

  float a0 = 0.f, a1 = 0.f, a2 = 0.f, a3 = 0.f;
  for (int n = s + wid; n < e; n += 4) {
    float alpha = expf(gate[n] - mglob) / S;
    const float* p = (lane < 32) ? (h + (size_t)n * 128 + 4 * lane)
                                 : (h0 + (size_t)n * 128 + 4 * (lane - 32));
    float4 v = *(const float4*)p;
    a0 += alpha * v.x; a1 += alpha * v.y; a2 += alpha * v.z; a3 += alpha * v.w;
  }
  facc[wid * 256 + 4 * lane + 0] = a0;
  facc[wid * 256 + 4 * lane + 1] = a1;
  facc[wid * 256 + 4 * lane + 2] = a2;
  facc[wid * 256 + 4 * lane + 3] = a3;
  __syncthreads();
  float rsum = facc[tid] + facc[256 + tid] + facc[512 + tid] + facc[768 + tid];
  float val = rsum * Wout[tid];
  val = wave_sum(val);
  if (lane == 0) sred[wid] = val;
  __syncthreads();
  if (tid == 0) out[g] = sred[0] + sred[1] + sred[2] + sred[3] + bout[0];
}

// ---------- host ----------
extern "C" void kernel_launch(void* const* d_in, const int* in_sizes, int n_in,
                              void* d_out, int out_size, void* d_ws, size_t ws_size,
                              hipStream_t stream) {
  (void)in_sizes; (void)n_in; (void)out_size; (void)ws_size;
  const int* type_ids = (const int*)d_in[0];
  const int* src      = (const int*)d_in[1];
  const int* dst      = (const int*)d_in[2];
  const int* etypes   = (const int*)d_in[3];
  const int* gid      = (const int*)d_in[4];
  const float* embed  = (const float*)d_in[5];
  const float* W_red  = (const float*)d_in[6];
  const float* b_red  = (const float*)d_in[7];
  const float* W_msg  = (const float*)d_in[8];
  const float* b_msg  = (const float*)d_in[9];
  const float* W_ih   = (const float*)d_in[10];
  const float* b_ih   = (const float*)d_in[11];
  const float* W_hh   = (const float*)d_in[12];
  const float* b_hh   = (const float*)d_in[13];
  const float* W_gate = (const float*)d_in[14];
  const float* b_gate = (const float*)d_in[15];
  const float* W_out  = (const float*)d_in[16];
  const float* b_out  = (const float*)d_in[17];

  char* p = (char*)d_ws;
  auto take = [&](size_t nb) { char* r = p; p += (nb + 255) & ~(size_t)255; return r; };
  float* hf            = (float*)take((size_t)NN * 128 * sizeof(float));
  float* h0b           = (float*)take((size_t)NN * 128 * sizeof(float));
  unsigned short* hbf  = (unsigned short*)take((size_t)NN * 128 * 2);
  unsigned short* abf  = (unsigned short*)take((size_t)NN * 128 * 2);
  unsigned short* WmsgF = (unsigned short*)take(49152 * 2);
  unsigned short* WihF  = (unsigned short*)take(49152 * 2);
  unsigned short* WhhF  = (unsigned short*)take(49152 * 2);
  float* WredT = (float*)take(64 * 128 * sizeof(float));
  float* gateb = (float*)take((size_t)NN * sizeof(float));
  int* deg3    = (int*)take((size_t)2 * 3 * NN * sizeof(int));
  int* cursor3 = deg3 + 3 * NN;
  int* rowst3x = (int*)take(((size_t)3 * NN + 1) * sizeof(int));
  int* payload = (int*)take((size_t)NE * sizeof(int));
  int* csum    = (int*)take(2048);
  int* bound   = (int*)take(512);

  // weight prep
  transpose_w<<<(128 * 64 + 255) / 256, 256, 0, stream>>>(W_red, WredT, 128, 64);
  pack_fragB<<<24, 256, 0, stream>>>(W_msg, WmsgF);
  pack_fragB<<<24, 256, 0, stream>>>(W_ih, WihF);
  pack_fragB<<<24, 256, 0, stream>>>(W_hh, WhhF);

  // CSR keyed by (etype, dst)
  const int L3 = 3 * NN;
  hipMemsetAsync(deg3, 0, (size_t)2 * L3 * sizeof(int), stream);
  count3_k<<<(NE + 255) / 256, 256, 0, stream>>>(dst, etypes, deg3);
  int nch = (L3 + 1023) / 1024;
  scan1<<<nch, 256, 0, stream>>>(deg3, rowst3x, csum, L3);
  scan2<<<1, 64, 0, stream>>>(csum, nch);
  scan3<<<(L3 + 255) / 256, 256, 0, stream>>>(rowst3x, csum, L3);
  set_last<<<1, 1, 0, stream>>>(rowst3x);
  fill3_k<<<(NE + 255) / 256, 256, 0, stream>>>(src, dst, etypes, rowst3x, cursor3, payload);

  // h0 = embed[type_ids] @ W_red^T + b_red ; hf = h0 ; hbf shadow
  gemm_cacheB<64><<<(NN + 63) / 64, 256, 0, stream>>>(
      embed, type_ids, WredT, 128, b_red, h0b, hf, NN);
  conv_bf16v<<<((NN * 128 / 4) + 255) / 256, 256, 0, stream>>>(hf, hbf, NN * 128 / 4);

  const int nblk = (NN + 63) / 64;
  for (int s6 = 0; s6 < 6; ++s6) {
    msg_mfma4<<<nblk, 256, 0, stream>>>((const unsigned*)hbf, rowst3x, payload,
                                        WmsgF, b_msg, abf);
    gru_mfma4<<<nblk, 256, 0, stream>>>(hf, hbf, abf, WihF, WhhF, b_ih, b_hh);
  }

  gate_k<<<(NN + 3) / 4, 256, 0, stream>>>(hf, h0b, W_gate, b_gate, gateb);
  bounds_k<<<1, 128, 0, stream>>>(gid, bound);
  pool_k<<<NG, 256, 0, stream>>>(hf, h0b, gateb, bound, W_out, b_out, (float*)d_out);
}